// Round 1
// baseline (608.122 us; speedup 1.0000x reference)
//
#include <hip/hip_runtime.h>

// LSTM-GCN single step from (H=0, C=0).
// Collapsed math: Fg gate dead (C_prev=0), cheb(H,..)=bh, peephole wc[0],wc[1] dead.
//
// R5: the R4 counting sort paid ~280 us in device-scope atomics (count_deg 142 us:
// WRITE_SIZE 100 MB = 3.2M x 32B sector write-through, one per atomic; reorder est
// ~130 us with returning cursor atomics + random scatter). Replace with a 2-level
// coarse-bucket sort (64 nodes/bucket): per-block LDS histograms -> non-atomic
// part[bin][block] matrix -> one 400k exclusive scan gives exact record offsets
// (no cursor atomics anywhere) -> deterministic re-scatter of packed 8B records
// via the cached store path -> per-bucket LDS-atomic accumulate fuses fine sort
// and gather. Only remaining global atomics: 1.6M fire-and-forget f32 deg adds.

#define FDIM 32
#define MAX_N 100000
#define MAX_E 1600000
#define CBSH 6                                // 64 nodes per coarse bucket
#define CB 64
#define MAX_NB ((MAX_N + CB - 1) / CB)        // 1563 buckets max
#define NBLK 256                              // blocks in each edge pass
#define SCAN_TILE 1024                        // elements per scan block (256 thr x 4)

__device__ float g_deg[MAX_N];                // degree -> dinv in place
__device__ int   g_part[MAX_NB * NBLK + 1];   // per-(bin,block) counts -> offsets
__device__ int   g_blk[1024];                 // scan block sums
__device__ uint2 g_rec[MAX_E];                // packed {src<<6|dst_low, nrm} by bucket
__device__ float g_tx1[MAX_N * FDIM];         // L_hat @ x

__global__ void zero_kernel(int n_nodes, int nbuck) {
    int i = blockIdx.x * blockDim.x + threadIdx.x;
    for (; i < n_nodes; i += gridDim.x * blockDim.x) g_deg[i] = 0.f;
    if (blockIdx.x == 0 && threadIdx.x == 0) g_part[nbuck * NBLK] = 0;  // scan sentinel
}

// One edge pass: deg[s] += w (global f32 atomic, fire-and-forget, self-loops
// excluded) and LDS coarse histogram of dst>>6, flushed NON-atomically to
// g_part[bin*NBLK + block].
__global__ __launch_bounds__(256) void hist_deg_kernel(const int* __restrict__ ei,
                                                       const float* __restrict__ w,
                                                       int E, int n_nodes, int nbuck,
                                                       int per_blk) {
    __shared__ int h[MAX_NB];
    for (int i = threadIdx.x; i < nbuck; i += 256) h[i] = 0;
    __syncthreads();
    int start = blockIdx.x * per_blk;
    int end = start + per_blk;
    if (end > E) end = E;
    for (int e = start + threadIdx.x; e < end; e += 256) {
        int s = ei[e];
        int d = ei[E + e];
        if ((unsigned)s >= (unsigned)n_nodes || (unsigned)d >= (unsigned)n_nodes) continue;
        if (s != d) unsafeAtomicAdd(&g_deg[s], w[e]);
        atomicAdd(&h[d >> CBSH], 1);          // LDS atomic
    }
    __syncthreads();
    for (int i = threadIdx.x; i < nbuck; i += 256)
        g_part[i * NBLK + blockIdx.x] = h[i]; // plain store, no atomics
}

__global__ void dinv_kernel(int n) {
    int i = blockIdx.x * blockDim.x + threadIdx.x;
    if (i >= n) return;
    float d = g_deg[i];
    g_deg[i] = (d > 0.f) ? rsqrtf(d) : 0.f;
}

// --- exclusive scan over g_part[0..n), 3 kernels (n = nbuck*NBLK + 1 <= ~400k) ---
__global__ __launch_bounds__(256) void scan1_kernel(int n) {
    __shared__ int sh[256];
    int tid = threadIdx.x;
    int base = blockIdx.x * SCAN_TILE + tid * 4;
    int v[4];
#pragma unroll
    for (int i = 0; i < 4; ++i) v[i] = (base + i < n) ? g_part[base + i] : 0;
    int tsum = v[0] + v[1] + v[2] + v[3];
    sh[tid] = tsum;
    __syncthreads();
    for (int off = 1; off < 256; off <<= 1) {
        int t = (tid >= off) ? sh[tid - off] : 0;
        __syncthreads();
        sh[tid] += t;
        __syncthreads();
    }
    if (tid == 255) g_blk[blockIdx.x] = sh[255];
    int run = sh[tid] - tsum;   // exclusive offset within block
#pragma unroll
    for (int i = 0; i < 4; ++i) {
        if (base + i < n) g_part[base + i] = run;
        run += v[i];
    }
}

__global__ __launch_bounds__(256) void scan2_kernel(int nb) {   // nb <= 1024
    __shared__ int sh[256];
    int tid = threadIdx.x;
    int base = tid * 4;
    int v[4];
#pragma unroll
    for (int i = 0; i < 4; ++i) v[i] = (base + i < nb) ? g_blk[base + i] : 0;
    int tsum = v[0] + v[1] + v[2] + v[3];
    sh[tid] = tsum;
    __syncthreads();
    for (int off = 1; off < 256; off <<= 1) {
        int t = (tid >= off) ? sh[tid - off] : 0;
        __syncthreads();
        sh[tid] += t;
        __syncthreads();
    }
    int run = sh[tid] - tsum;
#pragma unroll
    for (int i = 0; i < 4; ++i) {
        if (base + i < nb) g_blk[base + i] = run;
        run += v[i];
    }
}

__global__ void scan3_kernel(int n) {
    int off = g_blk[blockIdx.x];
    int base = blockIdx.x * SCAN_TILE + threadIdx.x * 4;
#pragma unroll
    for (int i = 0; i < 4; ++i) {
        int idx = base + i;
        if (idx < n) g_part[idx] += off;
    }
}

// Re-reads the IDENTICAL edge range as hist_deg_kernel; per-bin LDS cursors start
// at the scanned (bin,block) offsets, so record placement needs no global atomics.
__global__ __launch_bounds__(256) void scatter_kernel(const int* __restrict__ ei,
                                                      const float* __restrict__ w,
                                                      int E, int n_nodes, int nbuck,
                                                      int per_blk) {
    __shared__ int cur[MAX_NB];
    for (int i = threadIdx.x; i < nbuck; i += 256)
        cur[i] = g_part[i * NBLK + blockIdx.x];
    __syncthreads();
    int start = blockIdx.x * per_blk;
    int end = start + per_blk;
    if (end > E) end = E;
    for (int e = start + threadIdx.x; e < end; e += 256) {
        int s = ei[e];
        int d = ei[E + e];
        if ((unsigned)s >= (unsigned)n_nodes || (unsigned)d >= (unsigned)n_nodes) continue;
        float nrm = (s == d) ? 0.f : -g_deg[s] * w[e] * g_deg[d];  // g_deg holds dinv
        int pos = atomicAdd(&cur[d >> CBSH], 1);                   // LDS atomic
        g_rec[pos] = make_uint2(((unsigned)s << CBSH) | (unsigned)(d & (CB - 1)),
                                __float_as_uint(nrm));
    }
}

// One block per 64-node bucket: accumulate tx1 rows in an 8 KB LDS tile with
// ds_add_f32 (lane f -> bank f, conflict-free), coalesced write-out.
// Fuses the fine sort and the gather: records within a bucket need no order.
__global__ __launch_bounds__(256) void bucket_gather_kernel(const float* __restrict__ x,
                                                            int n_nodes, int nbuck) {
    __shared__ float acc[CB * FDIM];   // 8 KB
    int b = blockIdx.x;
    for (int i = threadIdx.x; i < CB * FDIM; i += 256) acc[i] = 0.f;
    int rs = g_part[b * NBLK];
    int re = g_part[(b + 1) * NBLK];   // b == nbuck-1 hits the sentinel (= total)
    __syncthreads();
    int g = threadIdx.x >> 5;          // 8 half-wave groups, one record each
    int f = threadIdx.x & 31;
    int i = rs + g;
    if (i < re) {
        uint2 r = g_rec[i];
        float xv = x[(r.x >> CBSH) * FDIM + f];
        while (true) {
            int in = i + 8;
            uint2 rn = r;
            float xvn = xv;
            bool more = (in < re);
            if (more) {                // software-prefetch next record + x row
                rn = g_rec[in];
                xvn = x[(rn.x >> CBSH) * FDIM + f];
            }
            atomicAdd(&acc[(r.x & (CB - 1)) * FDIM + f], __uint_as_float(r.y) * xv);
            if (!more) break;
            r = rn; xv = xvn; i = in;
        }
    }
    __syncthreads();
    int base = b << CBSH;
    for (int row = threadIdx.x >> 5; row < CB; row += 8) {
        int n = base + row;
        if (n < n_nodes) g_tx1[n * FDIM + f] = acc[row * FDIM + f];
    }
}

// 8 nodes per 256-thread block; thread (node, j) computes output feature j of
// gates i, c, o. Weights for the 3 live gates staged in LDS (24 KB).
__global__ __launch_bounds__(256) void gates_kernel(
    const float* __restrict__ x,
    const float* __restrict__ Wx, const float* __restrict__ bx,
    const float* __restrict__ bh, const float* __restrict__ wc,
    const float* __restrict__ bg, const float* __restrict__ lin_w,
    const float* __restrict__ lin_b, float* __restrict__ out, int n_nodes) {
    __shared__ float Ws[3 * 2048];      // gates {i,c,o} x K=2 x 32x32
    __shared__ float xs[8 * FDIM];
    __shared__ float ts[8 * FDIM];

    for (int idx = threadIdx.x; idx < 2048; idx += 256) {
        Ws[idx]          = Wx[0 * 2048 + idx];
        Ws[2048 + idx]   = Wx[2 * 2048 + idx];
        Ws[4096 + idx]   = Wx[3 * 2048 + idx];
    }
    int node0 = blockIdx.x * 8;
    {
        int n = node0 + (threadIdx.x >> 5);
        int f = threadIdx.x & 31;
        if (n < n_nodes) {
            xs[threadIdx.x] = x[n * FDIM + f];
            ts[threadIdx.x] = g_tx1[n * FDIM + f];
        }
    }
    __syncthreads();

    int ln = threadIdx.x >> 5;
    int j  = threadIdx.x & 31;
    int n  = node0 + ln;
    if (n >= n_nodes) return;

    const float* xr = &xs[ln * FDIM];
    const float* tr = &ts[ln * FDIM];
    float acc_i = 0.f, acc_c = 0.f, acc_o = 0.f;
#pragma unroll
    for (int k = 0; k < 32; ++k) {
        float xv = xr[k], tv = tr[k];
        int o0 = k * 32 + j;
        acc_i += xv * Ws[o0]          + tv * Ws[1024 + o0];
        acc_c += xv * Ws[2048 + o0]   + tv * Ws[3072 + o0];
        acc_o += xv * Ws[4096 + o0]   + tv * Ws[5120 + o0];
    }
    float bi = bx[0 * 32 + j] + bh[0 * 32 + j] + bg[0 * 32 + j];
    float bc = bx[2 * 32 + j] + bh[2 * 32 + j] + bg[2 * 32 + j];
    float bo = bx[3 * 32 + j] + bh[3 * 32 + j] + bg[3 * 32 + j];

    float I = 1.f / (1.f + __expf(-(acc_i + bi)));
    float T = tanhf(acc_c + bc);
    float C = I * T;                                    // Fg*C_prev = 0
    float O = 1.f / (1.f + __expf(-(acc_o + bo + wc[2 * 32 + j] * C)));
    float H = O * tanhf(C);
    float r = fmaxf(H, 0.f) * lin_w[j];
#pragma unroll
    for (int m = 16; m > 0; m >>= 1) r += __shfl_xor(r, m, 32);
    if (j == 0) out[n] = r + lin_b[0];
}

extern "C" void kernel_launch(void* const* d_in, const int* in_sizes, int n_in,
                              void* d_out, int out_size, void* d_ws, size_t ws_size,
                              hipStream_t stream) {
    const float* x     = (const float*)d_in[0];
    const int*   ei    = (const int*)d_in[1];      // int32 on device
    const float* w     = (const float*)d_in[2];
    const float* Wx    = (const float*)d_in[3];
    const float* bx    = (const float*)d_in[4];
    // d_in[5] = Wh: unused (H=0)
    const float* bh    = (const float*)d_in[6];
    const float* wc    = (const float*)d_in[7];
    const float* bg    = (const float*)d_in[8];
    const float* lin_w = (const float*)d_in[9];
    const float* lin_b = (const float*)d_in[10];
    float*       out   = (float*)d_out;

    int n_nodes = in_sizes[0] / FDIM;
    if (n_nodes > MAX_N) n_nodes = MAX_N;
    int E = in_sizes[2];
    if (E > MAX_E) E = MAX_E;

    int nbuck   = (n_nodes + CB - 1) >> CBSH;            // 1563 for N=100k
    int per_blk = (E + NBLK - 1) / NBLK;                 // 6250 edges/block
    int n_scan  = nbuck * NBLK + 1;                      // 400129
    int nb_scan = (n_scan + SCAN_TILE - 1) / SCAN_TILE;  // 391

    zero_kernel<<<512, 256, 0, stream>>>(n_nodes, nbuck);
    hist_deg_kernel<<<NBLK, 256, 0, stream>>>(ei, w, E, n_nodes, nbuck, per_blk);
    dinv_kernel<<<(n_nodes + 255) / 256, 256, 0, stream>>>(n_nodes);
    scan1_kernel<<<nb_scan, 256, 0, stream>>>(n_scan);
    scan2_kernel<<<1, 256, 0, stream>>>(nb_scan);
    scan3_kernel<<<nb_scan, 256, 0, stream>>>(n_scan);
    scatter_kernel<<<NBLK, 256, 0, stream>>>(ei, w, E, n_nodes, nbuck, per_blk);
    bucket_gather_kernel<<<nbuck, 256, 0, stream>>>(x, n_nodes, nbuck);
    gates_kernel<<<(n_nodes + 7) / 8, 256, 0, stream>>>(
        x, Wx, bx, bh, wc, bg, lin_w, lin_b, out, n_nodes);
}

// Round 2
// 603.329 us; speedup vs baseline: 1.0079x; 1.0079x over previous
//
#include <hip/hip_runtime.h>

// LSTM-GCN single step from (H=0, C=0).
// Collapsed math: Fg gate dead (C_prev=0), cheb(H,..)=bh, peephole wc[0],wc[1] dead.
//
// R6: R5's bucket_gather was latency-bound (317 us: 300 GB/s, VALU 5%, one record
// in flight per half-wave group, ~970 cy per dependent rec->x chain). Fix: depth-8
// software pipeline (8 recs + 8 x-rows in flight per group, static reg indexing).
// Also NBLK 256->512: hist/scatter edge passes were running at 1 block/CU.
// Global atomics remaining: 1.6M fire-and-forget f32 deg adds (hist_deg).

#define FDIM 32
#define MAX_N 100000
#define MAX_E 1600000
#define CBSH 6                                // 64 nodes per coarse bucket
#define CB 64
#define MAX_NB ((MAX_N + CB - 1) / CB)        // 1563 buckets max
#define NBLK 512                              // blocks in each edge pass
#define SCAN_TILE 1024                        // elements per scan block (256 thr x 4)
#define GDEPTH 8                              // records in flight per gather group

__device__ float g_deg[MAX_N];                // degree -> dinv in place
__device__ int   g_part[MAX_NB * NBLK + 1];   // per-(bin,block) counts -> offsets
__device__ int   g_blk[1024];                 // scan block sums
__device__ uint2 g_rec[MAX_E];                // packed {src<<6|dst_low, nrm} by bucket
__device__ float g_tx1[MAX_N * FDIM];         // L_hat @ x

__global__ void zero_kernel(int n_nodes, int nbuck) {
    int i = blockIdx.x * blockDim.x + threadIdx.x;
    for (; i < n_nodes; i += gridDim.x * blockDim.x) g_deg[i] = 0.f;
    if (blockIdx.x == 0 && threadIdx.x == 0) g_part[nbuck * NBLK] = 0;  // scan sentinel
}

// One edge pass: deg[s] += w (global f32 atomic, fire-and-forget, self-loops
// excluded) and LDS coarse histogram of dst>>6, flushed NON-atomically to
// g_part[bin*NBLK + block].
__global__ __launch_bounds__(256) void hist_deg_kernel(const int* __restrict__ ei,
                                                       const float* __restrict__ w,
                                                       int E, int n_nodes, int nbuck,
                                                       int per_blk) {
    __shared__ int h[MAX_NB];
    for (int i = threadIdx.x; i < nbuck; i += 256) h[i] = 0;
    __syncthreads();
    int start = blockIdx.x * per_blk;
    int end = start + per_blk;
    if (end > E) end = E;
    for (int e = start + threadIdx.x; e < end; e += 256) {
        int s = ei[e];
        int d = ei[E + e];
        if ((unsigned)s >= (unsigned)n_nodes || (unsigned)d >= (unsigned)n_nodes) continue;
        if (s != d) unsafeAtomicAdd(&g_deg[s], w[e]);
        atomicAdd(&h[d >> CBSH], 1);          // LDS atomic
    }
    __syncthreads();
    for (int i = threadIdx.x; i < nbuck; i += 256)
        g_part[i * NBLK + blockIdx.x] = h[i]; // plain store, no atomics
}

__global__ void dinv_kernel(int n) {
    int i = blockIdx.x * blockDim.x + threadIdx.x;
    if (i >= n) return;
    float d = g_deg[i];
    g_deg[i] = (d > 0.f) ? rsqrtf(d) : 0.f;
}

// --- exclusive scan over g_part[0..n), 3 kernels (n = nbuck*NBLK + 1 <= ~800k) ---
__global__ __launch_bounds__(256) void scan1_kernel(int n) {
    __shared__ int sh[256];
    int tid = threadIdx.x;
    int base = blockIdx.x * SCAN_TILE + tid * 4;
    int v[4];
#pragma unroll
    for (int i = 0; i < 4; ++i) v[i] = (base + i < n) ? g_part[base + i] : 0;
    int tsum = v[0] + v[1] + v[2] + v[3];
    sh[tid] = tsum;
    __syncthreads();
    for (int off = 1; off < 256; off <<= 1) {
        int t = (tid >= off) ? sh[tid - off] : 0;
        __syncthreads();
        sh[tid] += t;
        __syncthreads();
    }
    if (tid == 255) g_blk[blockIdx.x] = sh[255];
    int run = sh[tid] - tsum;   // exclusive offset within block
#pragma unroll
    for (int i = 0; i < 4; ++i) {
        if (base + i < n) g_part[base + i] = run;
        run += v[i];
    }
}

__global__ __launch_bounds__(256) void scan2_kernel(int nb) {   // nb <= 1024
    __shared__ int sh[256];
    int tid = threadIdx.x;
    int base = tid * 4;
    int v[4];
#pragma unroll
    for (int i = 0; i < 4; ++i) v[i] = (base + i < nb) ? g_blk[base + i] : 0;
    int tsum = v[0] + v[1] + v[2] + v[3];
    sh[tid] = tsum;
    __syncthreads();
    for (int off = 1; off < 256; off <<= 1) {
        int t = (tid >= off) ? sh[tid - off] : 0;
        __syncthreads();
        sh[tid] += t;
        __syncthreads();
    }
    int run = sh[tid] - tsum;
#pragma unroll
    for (int i = 0; i < 4; ++i) {
        if (base + i < nb) g_blk[base + i] = run;
        run += v[i];
    }
}

__global__ void scan3_kernel(int n) {
    int off = g_blk[blockIdx.x];
    int base = blockIdx.x * SCAN_TILE + threadIdx.x * 4;
#pragma unroll
    for (int i = 0; i < 4; ++i) {
        int idx = base + i;
        if (idx < n) g_part[idx] += off;
    }
}

// Re-reads the IDENTICAL edge range as hist_deg_kernel; per-bin LDS cursors start
// at the scanned (bin,block) offsets, so record placement needs no global atomics.
__global__ __launch_bounds__(256) void scatter_kernel(const int* __restrict__ ei,
                                                      const float* __restrict__ w,
                                                      int E, int n_nodes, int nbuck,
                                                      int per_blk) {
    __shared__ int cur[MAX_NB];
    for (int i = threadIdx.x; i < nbuck; i += 256)
        cur[i] = g_part[i * NBLK + blockIdx.x];
    __syncthreads();
    int start = blockIdx.x * per_blk;
    int end = start + per_blk;
    if (end > E) end = E;
    for (int e = start + threadIdx.x; e < end; e += 256) {
        int s = ei[e];
        int d = ei[E + e];
        if ((unsigned)s >= (unsigned)n_nodes || (unsigned)d >= (unsigned)n_nodes) continue;
        float nrm = (s == d) ? 0.f : -g_deg[s] * w[e] * g_deg[d];  // g_deg holds dinv
        int pos = atomicAdd(&cur[d >> CBSH], 1);                   // LDS atomic
        g_rec[pos] = make_uint2(((unsigned)s << CBSH) | (unsigned)(d & (CB - 1)),
                                __float_as_uint(nrm));
    }
}

// One block per 64-node bucket: accumulate tx1 rows in an 8 KB LDS tile with
// ds_add_f32 (lane f -> bank f, 2-way within wave = free), coalesced write-out.
// Depth-8 register pipeline per half-wave group: 8 record loads issued together,
// then 8 independent x-row loads, then 8 LDS atomics -> 64 records in flight
// per block instead of 8 (R5 was one dependent rec->x chain per group).
__global__ __launch_bounds__(256) void bucket_gather_kernel(const float* __restrict__ x,
                                                            int n_nodes, int nbuck) {
    __shared__ float acc[CB * FDIM];   // 8 KB
    int b = blockIdx.x;
    for (int i = threadIdx.x; i < CB * FDIM; i += 256) acc[i] = 0.f;
    int rs = g_part[b * NBLK];
    int re = g_part[(b + 1) * NBLK];   // b == nbuck-1 hits the sentinel (= total)
    __syncthreads();
    int g = threadIdx.x >> 5;          // 8 half-wave groups
    int f = threadIdx.x & 31;
    for (int i = rs + g; i < re; i += 8 * GDEPTH) {
        uint2 r[GDEPTH];
        float xv[GDEPTH];
#pragma unroll
        for (int m = 0; m < GDEPTH; ++m) {
            int idx = i + 8 * m;
            if (idx < re) r[m] = g_rec[idx];
        }
#pragma unroll
        for (int m = 0; m < GDEPTH; ++m) {
            int idx = i + 8 * m;
            if (idx < re) xv[m] = x[(r[m].x >> CBSH) * FDIM + f];
        }
#pragma unroll
        for (int m = 0; m < GDEPTH; ++m) {
            int idx = i + 8 * m;
            if (idx < re)
                atomicAdd(&acc[(r[m].x & (CB - 1)) * FDIM + f],
                          __uint_as_float(r[m].y) * xv[m]);
        }
    }
    __syncthreads();
    int base = b << CBSH;
    for (int row = threadIdx.x >> 5; row < CB; row += 8) {
        int n = base + row;
        if (n < n_nodes) g_tx1[n * FDIM + f] = acc[row * FDIM + f];
    }
}

// 8 nodes per 256-thread block; thread (node, j) computes output feature j of
// gates i, c, o. Weights for the 3 live gates staged in LDS (24 KB).
__global__ __launch_bounds__(256) void gates_kernel(
    const float* __restrict__ x,
    const float* __restrict__ Wx, const float* __restrict__ bx,
    const float* __restrict__ bh, const float* __restrict__ wc,
    const float* __restrict__ bg, const float* __restrict__ lin_w,
    const float* __restrict__ lin_b, float* __restrict__ out, int n_nodes) {
    __shared__ float Ws[3 * 2048];      // gates {i,c,o} x K=2 x 32x32
    __shared__ float xs[8 * FDIM];
    __shared__ float ts[8 * FDIM];

    for (int idx = threadIdx.x; idx < 2048; idx += 256) {
        Ws[idx]          = Wx[0 * 2048 + idx];
        Ws[2048 + idx]   = Wx[2 * 2048 + idx];
        Ws[4096 + idx]   = Wx[3 * 2048 + idx];
    }
    int node0 = blockIdx.x * 8;
    {
        int n = node0 + (threadIdx.x >> 5);
        int f = threadIdx.x & 31;
        if (n < n_nodes) {
            xs[threadIdx.x] = x[n * FDIM + f];
            ts[threadIdx.x] = g_tx1[n * FDIM + f];
        }
    }
    __syncthreads();

    int ln = threadIdx.x >> 5;
    int j  = threadIdx.x & 31;
    int n  = node0 + ln;
    if (n >= n_nodes) return;

    const float* xr = &xs[ln * FDIM];
    const float* tr = &ts[ln * FDIM];
    float acc_i = 0.f, acc_c = 0.f, acc_o = 0.f;
#pragma unroll
    for (int k = 0; k < 32; ++k) {
        float xv = xr[k], tv = tr[k];
        int o0 = k * 32 + j;
        acc_i += xv * Ws[o0]          + tv * Ws[1024 + o0];
        acc_c += xv * Ws[2048 + o0]   + tv * Ws[3072 + o0];
        acc_o += xv * Ws[4096 + o0]   + tv * Ws[5120 + o0];
    }
    float bi = bx[0 * 32 + j] + bh[0 * 32 + j] + bg[0 * 32 + j];
    float bc = bx[2 * 32 + j] + bh[2 * 32 + j] + bg[2 * 32 + j];
    float bo = bx[3 * 32 + j] + bh[3 * 32 + j] + bg[3 * 32 + j];

    float I = 1.f / (1.f + __expf(-(acc_i + bi)));
    float T = tanhf(acc_c + bc);
    float C = I * T;                                    // Fg*C_prev = 0
    float O = 1.f / (1.f + __expf(-(acc_o + bo + wc[2 * 32 + j] * C)));
    float H = O * tanhf(C);
    float r = fmaxf(H, 0.f) * lin_w[j];
#pragma unroll
    for (int m = 16; m > 0; m >>= 1) r += __shfl_xor(r, m, 32);
    if (j == 0) out[n] = r + lin_b[0];
}

extern "C" void kernel_launch(void* const* d_in, const int* in_sizes, int n_in,
                              void* d_out, int out_size, void* d_ws, size_t ws_size,
                              hipStream_t stream) {
    const float* x     = (const float*)d_in[0];
    const int*   ei    = (const int*)d_in[1];      // int32 on device
    const float* w     = (const float*)d_in[2];
    const float* Wx    = (const float*)d_in[3];
    const float* bx    = (const float*)d_in[4];
    // d_in[5] = Wh: unused (H=0)
    const float* bh    = (const float*)d_in[6];
    const float* wc    = (const float*)d_in[7];
    const float* bg    = (const float*)d_in[8];
    const float* lin_w = (const float*)d_in[9];
    const float* lin_b = (const float*)d_in[10];
    float*       out   = (float*)d_out;

    int n_nodes = in_sizes[0] / FDIM;
    if (n_nodes > MAX_N) n_nodes = MAX_N;
    int E = in_sizes[2];
    if (E > MAX_E) E = MAX_E;

    int nbuck   = (n_nodes + CB - 1) >> CBSH;            // 1563 for N=100k
    int per_blk = (E + NBLK - 1) / NBLK;                 // 3125 edges/block
    int n_scan  = nbuck * NBLK + 1;                      // 800257
    int nb_scan = (n_scan + SCAN_TILE - 1) / SCAN_TILE;  // 782 (<= 1024 for scan2)

    zero_kernel<<<512, 256, 0, stream>>>(n_nodes, nbuck);
    hist_deg_kernel<<<NBLK, 256, 0, stream>>>(ei, w, E, n_nodes, nbuck, per_blk);
    dinv_kernel<<<(n_nodes + 255) / 256, 256, 0, stream>>>(n_nodes);
    scan1_kernel<<<nb_scan, 256, 0, stream>>>(n_scan);
    scan2_kernel<<<1, 256, 0, stream>>>(nb_scan);
    scan3_kernel<<<nb_scan, 256, 0, stream>>>(n_scan);
    scatter_kernel<<<NBLK, 256, 0, stream>>>(ei, w, E, n_nodes, nbuck, per_blk);
    bucket_gather_kernel<<<nbuck, 256, 0, stream>>>(x, n_nodes, nbuck);
    gates_kernel<<<(n_nodes + 7) / 8, 256, 0, stream>>>(
        x, Wx, bx, bh, wc, bg, lin_w, lin_b, out, n_nodes);
}